// Round 2
// baseline (3554.514 us; speedup 1.0000x reference)
//
#include <hip/hip_runtime.h>
#include <stdint.h>

// ---------------------------------------------------------------------------
// SNN categorical policy forward (B=1024, C_IN=8, HID=300, OUT=2, T=300)
// One block per batch element b; 320 threads (5 waves); fully fused.
//
// Numerics strategy ("canonical pipeline"):
//  - fc1: left-to-right f32 add of selected weights (exact replication of any
//    c-ordered f32 reference, since enc bits make products exact).
//  - psp: direct truncated FIR with the f32-rounded SRM taps, f64 accumulate,
//    rounded to f32 at the tensor boundary (correctly rounded result).
//  - spike scan: exact-order f32 ops via __f*_rn (no FMA contraction), with
//    f32-rounded constants a=f32(e^-0.5), A=f32(-10e), theta=10.
//  - fc2: f64-exact sum of selected W2 weights -> f32.
//  - head: threefry2x32 PARTITIONABLE random bits (JAX >= 0.4.30 default):
//    bits[i] = o0 ^ o1 of threefry2x32(key=(0,42), ctr=(0, i)), i = 2b+j.
//    (R1 failure was the legacy pre-partitionable counter layout.)
// ---------------------------------------------------------------------------

#define NB    1024
#define CIN   8
#define HID   300
#define TLEN  300
#define KTAP  99          // taps j=1..99 (k_0 == 0)
#define THETA 10.0f

// LDS layout (bytes)
//  kD    double[100]      [0,      800)
//  maskL uint64[300*5]    [800,    12800)
//  ring  float[300*99]    [12800,  131600)
//  encL  float[2400]      [131600, 141200)
//  zL    float[2*304]     [141200, 143632)
//  u2L   float[2*304]     [143632, 146064)
//  lgL   float[2]         [146064, 146072)
#define LDS_BYTES 146080

__device__ __forceinline__ void threefry2x32(uint32_t c0, uint32_t c1,
                                             uint32_t& o0, uint32_t& o1) {
  const uint32_t k0 = 0u, k1 = 42u;
  const uint32_t k2 = k0 ^ k1 ^ 0x1BD11BDAu;
  uint32_t x0 = c0 + k0, x1 = c1 + k1;
#define TFR(r) { x0 += x1; x1 = (x1 << (r)) | (x1 >> (32 - (r))); x1 ^= x0; }
  TFR(13) TFR(15) TFR(26) TFR(6)  x0 += k1; x1 += k2 + 1u;
  TFR(17) TFR(29) TFR(16) TFR(24) x0 += k2; x1 += k0 + 2u;
  TFR(13) TFR(15) TFR(26) TFR(6)  x0 += k0; x1 += k1 + 3u;
  TFR(17) TFR(29) TFR(16) TFR(24) x0 += k1; x1 += k2 + 4u;
  TFR(13) TFR(15) TFR(26) TFR(6)  x0 += k2; x1 += k0 + 5u;
#undef TFR
  o0 = x0; o1 = x1;
}

__device__ __forceinline__ float jax_uniform_from_bits(uint32_t bits) {
  // jax._src.random._uniform for float32: (bits>>9 | 0x3f800000) - 1, then
  // * (maxval-minval) + minval with minval=tiny; (1-tiny) rounds to 1.0f.
  uint32_t fb = (bits >> 9) | 0x3F800000u;
  float f = __uint_as_float(fb) - 1.0f;
  const float tiny = 1.17549435e-38f;
  float u = __fadd_rn(f, tiny);
  return fmaxf(tiny, u);
}

__global__ __launch_bounds__(320)
void snn_policy_kernel(const float* __restrict__ enc,
                       const float* __restrict__ W1,
                       const float* __restrict__ W2,
                       float* __restrict__ out) {
  extern __shared__ char smem[];
  double*             kD    = (double*)(smem);
  unsigned long long* maskL = (unsigned long long*)(smem + 800);
  float*              ring  = (float*)(smem + 12800);
  float*              encL  = (float*)(smem + 131600);
  float*              zL    = (float*)(smem + 141200);
  float*              u2L   = (float*)(smem + 143632);
  float*              lgL   = (float*)(smem + 146064);

  const int tid = threadIdx.x;
  const int b   = blockIdx.x;

  const float arf = (float)0.6065306597126334;   // f32(exp(-0.5))
  const float Af  = (float)-27.182818284590452;  // f32(-scaleRef*theta*e*Ts/tauRef)

  // ---- SRM taps: f32 values of (j/10)*exp(1 - j/10), held as f64
  if (tid < 100) {
    int j = tid;
    float q   = (float)j / 10.0f;
    float arg = 1.0f - q;
    float ef  = (float)exp((double)arg);   // correctly-rounded f32 exp
    kD[j] = (double)__fmul_rn(q, ef);      // kD[0] = 0
  }
  // ---- stage encoded_input[b] : [8][300]
  for (int i = tid; i < CIN * TLEN; i += 320)
    encL[i] = enc[b * (CIN * TLEN) + i];
  __syncthreads();

  // =========================== layer 1 ===================================
  const int h  = tid;
  const int hh = (h < HID) ? h : (HID - 1);
  const int hb = hh * KTAP;
  float w1f[8];
#pragma unroll
  for (int c = 0; c < 8; ++c)
    w1f[c] = (h < HID) ? W1[h * 8 + c] : 0.0f;

  {
    float RX = 0.0f, RY = 0.0f;
    for (int t = 0; t < TLEN; ++t) {
      // u_mem[t] = sum_{j=1..min(t,99)} k_j * x[t-j]   (f64 accumulate)
      double acc = 0.0;
      const int jmax = (t < KTAP) ? t : KTAP;
      const int s0   = (t - 1) % KTAP;              // slot of x[t-1] (t>=1)
      int j = 1;
      const int len1 = (jmax < s0 + 1) ? jmax : (s0 + 1);
      int s = s0;
      for (; j <= len1; ++j, --s)
        acc += kD[j] * (double)ring[hb + s];
      for (s = KTAP - 1; j <= jmax; ++j, --s)
        acc += kD[j] * (double)ring[hb + s];
      float umem = (float)acc;

      // x[t]: left-to-right f32 sum of selected weights (exact replication)
      float xf = 0.0f;
#pragma unroll
      for (int c = 0; c < 8; ++c)
        xf = __fadd_rn(xf, __fmul_rn(encL[c * TLEN + t], w1f[c]));
      if (h < HID) ring[hb + (t % KTAP)] = xf;      // overwrite x[t-99] after use

      // spike step (exact f32 order)
      float v  = __fsub_rn(__fadd_rn(umem, RX), THETA);
      bool  sp = (v >= 0.0f) && (h < HID);
      unsigned long long bal = __ballot(sp);
      if ((tid & 63) == 0) maskL[t * 5 + (tid >> 6)] = bal;
      float sf = sp ? 1.0f : 0.0f;
      float y2 = __fadd_rn(RY, __fmul_rn(Af, sf));
      RX = __fmul_rn(arf, __fadd_rn(RX, y2));
      RY = __fmul_rn(arf, y2);
    }
  }
  __syncthreads();

  // =========================== layer 2 fc ================================
  if (tid < TLEN) {
    const int t = tid;
    double z0 = 0.0, z1 = 0.0;
#pragma unroll
    for (int w5 = 0; w5 < 5; ++w5) {
      unsigned long long mm = maskL[t * 5 + w5];
      const int hbase = w5 * 64;
      const int kend  = (w5 == 4) ? (HID - 256) : 64;
      for (int k = 0; k < kend; ++k) {
        if (mm & 1ull) {
          z0 += (double)W2[hbase + k];
          z1 += (double)W2[HID + hbase + k];
        }
        mm >>= 1;
      }
    }
    zL[t]       = (float)z0;
    zL[304 + t] = (float)z1;
  }
  __syncthreads();

  // =========================== layer 2 psp ===============================
  if (tid < TLEN) {
    const int t = tid;
    double a0 = 0.0, a1 = 0.0;
    const int jmax = (t < KTAP) ? t : KTAP;
    for (int j = 1; j <= jmax; ++j) {
      double kk = kD[j];
      a0 += kk * (double)zL[t - j];
      a1 += kk * (double)zL[304 + t - j];
    }
    u2L[t]       = (float)a0;
    u2L[304 + t] = (float)a1;
  }
  __syncthreads();

  // =========================== layer 2 spike + count =====================
  if (tid < 2) {
    float RX = 0.0f, RY = 0.0f;
    int cnt = 0;
    for (int t = 0; t < TLEN; ++t) {
      float u  = u2L[tid * 304 + t];
      float v  = __fsub_rn(__fadd_rn(u, RX), THETA);
      bool  sp = (v >= 0.0f);
      cnt += sp ? 1 : 0;
      float sf = sp ? 1.0f : 0.0f;
      float y2 = __fadd_rn(RY, __fmul_rn(Af, sf));
      RX = __fmul_rn(arf, __fadd_rn(RX, y2));
      RY = __fmul_rn(arf, y2);
    }
    lgL[tid] = (float)cnt;
  }
  __syncthreads();

  // =========================== head ======================================
  if (tid == 0) {
    float l0 = lgL[0], l1 = lgL[1];
    // JAX partitionable threefry random bits (default since 0.4.30):
    // element flat index i gets counter (hi,lo)=(0,i); 32-bit word = o0 ^ o1.
    uint32_t o0, o1;
    threefry2x32(0u, 2u * (uint32_t)b, o0, o1);
    float g0 = -logf(-logf(jax_uniform_from_bits(o0 ^ o1)));
    threefry2x32(0u, 2u * (uint32_t)b + 1u, o0, o1);
    float g1 = -logf(-logf(jax_uniform_from_bits(o0 ^ o1)));

    float v0 = __fadd_rn(l0, g0);
    float v1 = __fadd_rn(l1, g1);
    int   pi = (v1 > v0) ? 1 : 0;           // argmax, first index on tie
    float m   = fmaxf(l0, l1);
    float s0f = __fsub_rn(l0, m), s1f = __fsub_rn(l1, m);
    float lse = logf(__fadd_rn(expf(s0f), expf(s1f)));
    float lp  = __fsub_rn(pi ? s1f : s0f, lse);

    out[2 * b + 0]   = l0;
    out[2 * b + 1]   = l1;
    out[2048 + b]    = (float)pi;
    out[3072 + b]    = lp;
  }
}

extern "C" void kernel_launch(void* const* d_in, const int* in_sizes, int n_in,
                              void* d_out, int out_size, void* d_ws, size_t ws_size,
                              hipStream_t stream) {
  const float* enc = (const float*)d_in[0];
  const float* W1  = (const float*)d_in[1];
  const float* W2  = (const float*)d_in[2];
  float* out = (float*)d_out;

  // allow >64KB dynamic LDS (146 KB of 160 KB/CU); host-side, capture-safe
  hipFuncSetAttribute((const void*)snn_policy_kernel,
                      hipFuncAttributeMaxDynamicSharedMemorySize, LDS_BYTES);

  snn_policy_kernel<<<dim3(NB), dim3(320), LDS_BYTES, stream>>>(enc, W1, W2, out);
}

// Round 3
// 1553.512 us; speedup vs baseline: 2.2881x; 2.2881x over previous
//
#include <hip/hip_runtime.h>
#include <stdint.h>

// ---------------------------------------------------------------------------
// SNN categorical policy forward (B=1024, C_IN=8, HID=300, OUT=2, T=300)
//
// R3 restructure: two kernels.
//  K1 (layer 1): grid (5 h-chunks, 1024 b), 64 threads (1 wave). Each lane
//     owns neuron h = bh*64+lane. x-history lives in a 109-register sliding
//     window; FIR processes 10 outputs per iteration with 10 independent f64
//     accumulator chains (j ascending 1..99 -> f64 chain bit-identical to the
//     verified R2 kernel; zero-padded history adds exact +0.0 terms).
//     Group-convert: per 10-tap group, convert the 19 needed window f32s to
//     f64 once, reuse across 100 FMAs. Spike masks via ballot -> d_ws.
//  K2 (layer 2 + head): per-b block, 320 threads; masks/W2(f64)/taps staged
//     in LDS; fc2 flat-ascending branchless cndmask chain (bit-identical);
//     psp2/scan2/head exactly as the verified R2 kernel.
// ---------------------------------------------------------------------------

#define NB    1024
#define CIN   8
#define HID   300
#define TLEN  300
#define KTAP  99
#define THETA 10.0f
#define TB    10            // outputs per FIR block-iter (300 = 30*10)
#define WIN   109           // x-history window: 99 + TB

__device__ __forceinline__ void threefry2x32(uint32_t c0, uint32_t c1,
                                             uint32_t& o0, uint32_t& o1) {
  const uint32_t k0 = 0u, k1 = 42u;
  const uint32_t k2 = k0 ^ k1 ^ 0x1BD11BDAu;
  uint32_t x0 = c0 + k0, x1 = c1 + k1;
#define TFR(r) { x0 += x1; x1 = (x1 << (r)) | (x1 >> (32 - (r))); x1 ^= x0; }
  TFR(13) TFR(15) TFR(26) TFR(6)  x0 += k1; x1 += k2 + 1u;
  TFR(17) TFR(29) TFR(16) TFR(24) x0 += k2; x1 += k0 + 2u;
  TFR(13) TFR(15) TFR(26) TFR(6)  x0 += k0; x1 += k1 + 3u;
  TFR(17) TFR(29) TFR(16) TFR(24) x0 += k1; x1 += k2 + 4u;
  TFR(13) TFR(15) TFR(26) TFR(6)  x0 += k2; x1 += k0 + 5u;
#undef TFR
  o0 = x0; o1 = x1;
}

__device__ __forceinline__ float jax_uniform_from_bits(uint32_t bits) {
  uint32_t fb = (bits >> 9) | 0x3F800000u;
  float f = __uint_as_float(fb) - 1.0f;
  const float tiny = 1.17549435e-38f;
  float u = __fadd_rn(f, tiny);
  return fmaxf(tiny, u);
}

// ======================= Kernel 1: layer-1 SNN ============================
__global__ __launch_bounds__(64)
void snn_l1_kernel(const float* __restrict__ enc,
                   const float* __restrict__ W1,
                   unsigned long long* __restrict__ maskG) {
  __shared__ double kD[100];
  __shared__ float  encL[CIN * TLEN];

  const int lane = threadIdx.x;
  const int bh   = blockIdx.x;          // h-chunk [0,5)
  const int b    = blockIdx.y;
  const int h    = bh * 64 + lane;

  // taps: identical formula to verified R2 kernel
  for (int j = lane; j < 100; j += 64) {
    float q   = (float)j / 10.0f;
    float ef  = (float)exp((double)(1.0f - q));
    kD[j] = (double)__fmul_rn(q, ef);
  }
  for (int i = lane; i < CIN * TLEN; i += 64)
    encL[i] = enc[b * (CIN * TLEN) + i];
  __syncthreads();

  float w1f[8];
#pragma unroll
  for (int c = 0; c < 8; ++c)
    w1f[c] = (h < HID) ? W1[h * 8 + c] : 0.0f;

  const float arf = (float)0.6065306597126334;   // f32(exp(-0.5))
  const float Af  = (float)-27.182818284590452;  // f32(-10e)

  float W[WIN];
#pragma unroll
  for (int m = 0; m < WIN; ++m) W[m] = 0.0f;

  float RX = 0.0f, RY = 0.0f;
  unsigned long long* mptr = maskG + ((size_t)b * TLEN) * 5 + bh;

  for (int tb = 0; tb < TLEN / TB; ++tb) {
    const int t0 = tb * TB;

    // ---- new x values x[t0..t0+9] (exact-order f32, as R2) ----
#pragma unroll
    for (int i = 0; i < TB; ++i) {
      float xf = 0.0f;
#pragma unroll
      for (int c = 0; c < 8; ++c)
        xf = __fadd_rn(xf, __fmul_rn(encL[c * TLEN + t0 + i], w1f[c]));
      W[99 + i] = xf;
    }

    // ---- FIR: acc[i] = sum_{j=1..99} kD[j] * x[t0+i-j], f64, j ascending --
    double acc[TB];
#pragma unroll
    for (int i = 0; i < TB; ++i) acc[i] = 0.0;

#pragma unroll
    for (int jg = 0; jg < 10; ++jg) {
      const int jlo = jg * 10 + 1;
      const int jhi = (jg == 9) ? 99 : (jg * 10 + 10);
      const int mlo = 99 - jhi;                 // lowest window index used
      const int mhi = 99 + (TB - 1) - jlo;      // highest window index used
      double X64[19];
#pragma unroll
      for (int m = mlo; m <= mhi; ++m)
        X64[m - mlo] = (double)W[m];
#pragma unroll
      for (int j = jlo; j <= jhi; ++j) {
        const double kk = kD[j];
#pragma unroll
        for (int i = 0; i < TB; ++i)
          acc[i] += kk * X64[99 + i - j - mlo];
      }
    }

    // ---- spike scan (exact f32 order, as R2) + ballot -> global mask ----
#pragma unroll
    for (int i = 0; i < TB; ++i) {
      float umem = (float)acc[i];
      float v  = __fsub_rn(__fadd_rn(umem, RX), THETA);
      bool  sp = (v >= 0.0f) && (h < HID);
      unsigned long long bal = __ballot(sp);
      if (lane == 0) mptr[(size_t)(t0 + i) * 5] = bal;
      float sf = sp ? 1.0f : 0.0f;
      float y2 = __fadd_rn(RY, __fmul_rn(Af, sf));
      RX = __fmul_rn(arf, __fadd_rn(RX, y2));
      RY = __fmul_rn(arf, y2);
    }

    // ---- slide window by TB ----
#pragma unroll
    for (int m = 0; m < 99; ++m) W[m] = W[m + TB];
  }
}

// ================== Kernel 2: layer-2 + head (per b) ======================
__global__ __launch_bounds__(320)
void snn_l2_kernel(const float* __restrict__ W2,
                   const unsigned long long* __restrict__ maskG,
                   float* __restrict__ out) {
  __shared__ double             kD[100];
  __shared__ double             W2D[2 * HID];
  __shared__ unsigned long long maskL[TLEN * 5];
  __shared__ double             zD[2 * 304];
  __shared__ float              u2L[2 * 304];
  __shared__ float              lgL[2];

  const int tid = threadIdx.x;
  const int b   = blockIdx.x;

  const float arf = (float)0.6065306597126334;
  const float Af  = (float)-27.182818284590452;

  for (int j = tid; j < 100; j += 320) {
    float q   = (float)j / 10.0f;
    float ef  = (float)exp((double)(1.0f - q));
    kD[j] = (double)__fmul_rn(q, ef);
  }
  for (int i = tid; i < 2 * HID; i += 320)
    W2D[i] = (double)W2[i];
  for (int i = tid; i < TLEN * 5; i += 320)
    maskL[i] = maskG[(size_t)b * (TLEN * 5) + i];
  __syncthreads();

  // ---- fc2: flat ascending-h f64 chain, branchless (bit-identical to R2) --
  if (tid < TLEN) {
    const int t = tid;
    double z0 = 0.0, z1 = 0.0;
#pragma unroll
    for (int w5 = 0; w5 < 5; ++w5) {
      const unsigned long long mm = maskL[t * 5 + w5];
      const int kend = (w5 == 4) ? (HID - 256) : 64;
      for (int k = 0; k < kend; ++k) {
        const bool bit = (mm >> k) & 1ull;
        const int  hh  = w5 * 64 + k;
        z0 += bit ? W2D[hh] : 0.0;
        z1 += bit ? W2D[HID + hh] : 0.0;
      }
    }
    zD[t]       = (double)((float)z0);   // f32-rounded at tensor boundary
    zD[304 + t] = (double)((float)z1);
  }
  __syncthreads();

  // ---- psp2 (f64 accumulate, j ascending — as R2) ----
  if (tid < TLEN) {
    const int t = tid;
    double a0 = 0.0, a1 = 0.0;
    const int jmax = (t < KTAP) ? t : KTAP;
    for (int j = 1; j <= jmax; ++j) {
      const double kk = kD[j];
      a0 += kk * zD[t - j];
      a1 += kk * zD[304 + t - j];
    }
    u2L[t]       = (float)a0;
    u2L[304 + t] = (float)a1;
  }
  __syncthreads();

  // ---- layer-2 spike scan + count (as R2) ----
  if (tid < 2) {
    float RX = 0.0f, RY = 0.0f;
    int cnt = 0;
    for (int t = 0; t < TLEN; ++t) {
      float u  = u2L[tid * 304 + t];
      float v  = __fsub_rn(__fadd_rn(u, RX), THETA);
      bool  sp = (v >= 0.0f);
      cnt += sp ? 1 : 0;
      float sf = sp ? 1.0f : 0.0f;
      float y2 = __fadd_rn(RY, __fmul_rn(Af, sf));
      RX = __fmul_rn(arf, __fadd_rn(RX, y2));
      RY = __fmul_rn(arf, y2);
    }
    lgL[tid] = (float)cnt;
  }
  __syncthreads();

  // ---- head (as R2, verified) ----
  if (tid == 0) {
    float l0 = lgL[0], l1 = lgL[1];
    uint32_t o0, o1;
    threefry2x32(0u, 2u * (uint32_t)b, o0, o1);
    float g0 = -logf(-logf(jax_uniform_from_bits(o0 ^ o1)));
    threefry2x32(0u, 2u * (uint32_t)b + 1u, o0, o1);
    float g1 = -logf(-logf(jax_uniform_from_bits(o0 ^ o1)));

    float v0 = __fadd_rn(l0, g0);
    float v1 = __fadd_rn(l1, g1);
    int   pi = (v1 > v0) ? 1 : 0;
    float m   = fmaxf(l0, l1);
    float s0f = __fsub_rn(l0, m), s1f = __fsub_rn(l1, m);
    float lse = logf(__fadd_rn(expf(s0f), expf(s1f)));
    float lp  = __fsub_rn(pi ? s1f : s0f, lse);

    out[2 * b + 0] = l0;
    out[2 * b + 1] = l1;
    out[2048 + b]  = (float)pi;
    out[3072 + b]  = lp;
  }
}

extern "C" void kernel_launch(void* const* d_in, const int* in_sizes, int n_in,
                              void* d_out, int out_size, void* d_ws, size_t ws_size,
                              hipStream_t stream) {
  const float* enc = (const float*)d_in[0];
  const float* W1  = (const float*)d_in[1];
  const float* W2  = (const float*)d_in[2];
  float* out = (float*)d_out;

  unsigned long long* maskG = (unsigned long long*)d_ws;  // 1024*300*5*8 = 12.3 MB

  snn_l1_kernel<<<dim3(5, NB), dim3(64), 0, stream>>>(enc, W1, maskG);
  snn_l2_kernel<<<dim3(NB), dim3(320), 0, stream>>>(W2, maskG, out);
}

// Round 4
// 1312.247 us; speedup vs baseline: 2.7087x; 1.1839x over previous
//
#include <hip/hip_runtime.h>
#include <stdint.h>

// ---------------------------------------------------------------------------
// SNN categorical policy forward (B=1024, C_IN=8, HID=300, OUT=2, T=300)
//
// R4: register-window direct f64 FIR with spill control.
//  K1: grid (5,1024), 64 threads (1 wave). Lane owns h. x-history in a
//      109-reg f32 sliding window, TB=10 outputs/tile, tap groups of 5
//      (X64[14] staging). sched_barrier(0) between phases/groups caps live
//      ranges (R3's 3.2 GB scratch spill came from scheduler hoisting).
//      f64 chain is j-ascending 1..99 -> bit-identical to verified R2/R3.
//  K2: unchanged from R3 (verified bit-exact).
// ---------------------------------------------------------------------------

#define NB    1024
#define CIN   8
#define HID   300
#define TLEN  300
#define KTAP  99
#define THETA 10.0f
#define TB    10

__device__ __forceinline__ void threefry2x32(uint32_t c0, uint32_t c1,
                                             uint32_t& o0, uint32_t& o1) {
  const uint32_t k0 = 0u, k1 = 42u;
  const uint32_t k2 = k0 ^ k1 ^ 0x1BD11BDAu;
  uint32_t x0 = c0 + k0, x1 = c1 + k1;
#define TFR(r) { x0 += x1; x1 = (x1 << (r)) | (x1 >> (32 - (r))); x1 ^= x0; }
  TFR(13) TFR(15) TFR(26) TFR(6)  x0 += k1; x1 += k2 + 1u;
  TFR(17) TFR(29) TFR(16) TFR(24) x0 += k2; x1 += k0 + 2u;
  TFR(13) TFR(15) TFR(26) TFR(6)  x0 += k0; x1 += k1 + 3u;
  TFR(17) TFR(29) TFR(16) TFR(24) x0 += k1; x1 += k2 + 4u;
  TFR(13) TFR(15) TFR(26) TFR(6)  x0 += k2; x1 += k0 + 5u;
#undef TFR
  o0 = x0; o1 = x1;
}

__device__ __forceinline__ float jax_uniform_from_bits(uint32_t bits) {
  uint32_t fb = (bits >> 9) | 0x3F800000u;
  float f = __uint_as_float(fb) - 1.0f;
  const float tiny = 1.17549435e-38f;
  float u = __fadd_rn(f, tiny);
  return fmaxf(tiny, u);
}

// ======================= Kernel 1: layer-1 SNN ============================
__global__ __launch_bounds__(64, 1)
void snn_l1_kernel(const float* __restrict__ enc,
                   const float* __restrict__ W1,
                   unsigned long long* __restrict__ maskG) {
  __shared__ double kD[100];
  __shared__ float  encL[CIN * TLEN];

  const int lane = threadIdx.x;
  const int bh   = blockIdx.x;          // h-chunk [0,5)
  const int b    = blockIdx.y;
  const int h    = bh * 64 + lane;

  // taps: identical formula to verified R2/R3 kernels
  for (int j = lane; j < 100; j += 64) {
    float q   = (float)j / 10.0f;
    float ef  = (float)exp((double)(1.0f - q));
    kD[j] = (double)__fmul_rn(q, ef);
  }
  for (int i = lane; i < CIN * TLEN; i += 64)
    encL[i] = enc[b * (CIN * TLEN) + i];
  __syncthreads();

  float w1f[8];
#pragma unroll
  for (int c = 0; c < 8; ++c)
    w1f[c] = (h < HID) ? W1[h * 8 + c] : 0.0f;

  const float arf = (float)0.6065306597126334;   // f32(exp(-0.5))
  const float Af  = (float)-27.182818284590452;  // f32(-10e)

  float W[99 + TB];
#pragma unroll
  for (int m = 0; m < 99 + TB; ++m) W[m] = 0.0f;

  float RX = 0.0f, RY = 0.0f;
  unsigned long long* mptr = maskG + b * (TLEN * 5) + bh;

  for (int tb = 0; tb < TLEN / TB; ++tb) {
    const int t0 = tb * TB;

    // ---- phase 1: new x values x[t0..t0+9] (exact-order f32, verified) ----
#pragma unroll
    for (int i = 0; i < TB; ++i) {
      float xf = 0.0f;
#pragma unroll
      for (int c = 0; c < 8; ++c)
        xf = __fadd_rn(xf, __fmul_rn(encL[c * TLEN + t0 + i], w1f[c]));
      W[99 + i] = xf;
    }
    __builtin_amdgcn_sched_barrier(0);

    // ---- phase 2: FIR, tap groups of 5, j ascending (bit-identical) ----
    double acc[TB];
#pragma unroll
    for (int i = 0; i < TB; ++i) acc[i] = 0.0;

#pragma unroll
    for (int g = 0; g < 20; ++g) {
      const int jlo = 5 * g + 1;
      const int jhi = (5 * g + 5 < 99) ? (5 * g + 5) : 99;
      const int nw  = (jhi - jlo) + TB;           // 14 (13 for g=19)
      double X64[14];
#pragma unroll
      for (int m = 0; m < nw; ++m)
        X64[m] = (double)W[99 - jhi + m];         // = x[t0 - jhi + m]
#pragma unroll
      for (int j = jlo; j <= jhi; ++j) {
        const double kk = kD[j];
#pragma unroll
        for (int i = 0; i < TB; ++i)
          acc[i] += kk * X64[i + jhi - j];        // = x[t0 + i - j]
      }
      __builtin_amdgcn_sched_barrier(0);
    }

    // ---- phase 3: spike scan (exact f32 order, verified) ----
#pragma unroll
    for (int i = 0; i < TB; ++i) {
      float umem = (float)acc[i];
      float v  = __fsub_rn(__fadd_rn(umem, RX), THETA);
      bool  sp = (v >= 0.0f) && (h < HID);
      unsigned long long bal = __ballot(sp);
      if (lane == 0) mptr[(t0 + i) * 5] = bal;
      float sf = sp ? 1.0f : 0.0f;
      float y2 = __fadd_rn(RY, __fmul_rn(Af, sf));
      RX = __fmul_rn(arf, __fadd_rn(RX, y2));
      RY = __fmul_rn(arf, y2);
    }
    __builtin_amdgcn_sched_barrier(0);

    // ---- phase 4: slide window by TB ----
#pragma unroll
    for (int m = 0; m < 99; ++m) W[m] = W[m + TB];
    __builtin_amdgcn_sched_barrier(0);
  }
}

// ================== Kernel 2: layer-2 + head (per b) ======================
__global__ __launch_bounds__(320)
void snn_l2_kernel(const float* __restrict__ W2,
                   const unsigned long long* __restrict__ maskG,
                   float* __restrict__ out) {
  __shared__ double             kD[100];
  __shared__ double             W2D[2 * HID];
  __shared__ unsigned long long maskL[TLEN * 5];
  __shared__ double             zD[2 * 304];
  __shared__ float              u2L[2 * 304];
  __shared__ float              lgL[2];

  const int tid = threadIdx.x;
  const int b   = blockIdx.x;

  const float arf = (float)0.6065306597126334;
  const float Af  = (float)-27.182818284590452;

  for (int j = tid; j < 100; j += 320) {
    float q   = (float)j / 10.0f;
    float ef  = (float)exp((double)(1.0f - q));
    kD[j] = (double)__fmul_rn(q, ef);
  }
  for (int i = tid; i < 2 * HID; i += 320)
    W2D[i] = (double)W2[i];
  for (int i = tid; i < TLEN * 5; i += 320)
    maskL[i] = maskG[(size_t)b * (TLEN * 5) + i];
  __syncthreads();

  // ---- fc2: flat ascending-h f64 chain, branchless (bit-identical) ----
  if (tid < TLEN) {
    const int t = tid;
    double z0 = 0.0, z1 = 0.0;
#pragma unroll
    for (int w5 = 0; w5 < 5; ++w5) {
      const unsigned long long mm = maskL[t * 5 + w5];
      const int kend = (w5 == 4) ? (HID - 256) : 64;
      for (int k = 0; k < kend; ++k) {
        const bool bit = (mm >> k) & 1ull;
        const int  hh  = w5 * 64 + k;
        z0 += bit ? W2D[hh] : 0.0;
        z1 += bit ? W2D[HID + hh] : 0.0;
      }
    }
    zD[t]       = (double)((float)z0);   // f32-rounded at tensor boundary
    zD[304 + t] = (double)((float)z1);
  }
  __syncthreads();

  // ---- psp2 (f64 accumulate, j ascending) ----
  if (tid < TLEN) {
    const int t = tid;
    double a0 = 0.0, a1 = 0.0;
    const int jmax = (t < KTAP) ? t : KTAP;
    for (int j = 1; j <= jmax; ++j) {
      const double kk = kD[j];
      a0 += kk * zD[t - j];
      a1 += kk * zD[304 + t - j];
    }
    u2L[t]       = (float)a0;
    u2L[304 + t] = (float)a1;
  }
  __syncthreads();

  // ---- layer-2 spike scan + count ----
  if (tid < 2) {
    float RX = 0.0f, RY = 0.0f;
    int cnt = 0;
    for (int t = 0; t < TLEN; ++t) {
      float u  = u2L[tid * 304 + t];
      float v  = __fsub_rn(__fadd_rn(u, RX), THETA);
      bool  sp = (v >= 0.0f);
      cnt += sp ? 1 : 0;
      float sf = sp ? 1.0f : 0.0f;
      float y2 = __fadd_rn(RY, __fmul_rn(Af, sf));
      RX = __fmul_rn(arf, __fadd_rn(RX, y2));
      RY = __fmul_rn(arf, y2);
    }
    lgL[tid] = (float)cnt;
  }
  __syncthreads();

  // ---- head (verified) ----
  if (tid == 0) {
    float l0 = lgL[0], l1 = lgL[1];
    uint32_t o0, o1;
    threefry2x32(0u, 2u * (uint32_t)b, o0, o1);
    float g0 = -logf(-logf(jax_uniform_from_bits(o0 ^ o1)));
    threefry2x32(0u, 2u * (uint32_t)b + 1u, o0, o1);
    float g1 = -logf(-logf(jax_uniform_from_bits(o0 ^ o1)));

    float v0 = __fadd_rn(l0, g0);
    float v1 = __fadd_rn(l1, g1);
    int   pi = (v1 > v0) ? 1 : 0;
    float m   = fmaxf(l0, l1);
    float s0f = __fsub_rn(l0, m), s1f = __fsub_rn(l1, m);
    float lse = logf(__fadd_rn(expf(s0f), expf(s1f)));
    float lp  = __fsub_rn(pi ? s1f : s0f, lse);

    out[2 * b + 0] = l0;
    out[2 * b + 1] = l1;
    out[2048 + b]  = (float)pi;
    out[3072 + b]  = lp;
  }
}

extern "C" void kernel_launch(void* const* d_in, const int* in_sizes, int n_in,
                              void* d_out, int out_size, void* d_ws, size_t ws_size,
                              hipStream_t stream) {
  const float* enc = (const float*)d_in[0];
  const float* W1  = (const float*)d_in[1];
  const float* W2  = (const float*)d_in[2];
  float* out = (float*)d_out;

  unsigned long long* maskG = (unsigned long long*)d_ws;  // 12.3 MB

  snn_l1_kernel<<<dim3(5, NB), dim3(64), 0, stream>>>(enc, W1, maskG);
  snn_l2_kernel<<<dim3(NB), dim3(320), 0, stream>>>(W2, maskG, out);
}